// Round 9
// baseline (56438.354 us; speedup 1.0000x reference)
//
#include <hip/hip_runtime.h>

typedef float f32x2 __attribute__((ext_vector_type(2)));
typedef float f32x4 __attribute__((ext_vector_type(4)));

#define BATCH 32
#define SEQT  4096
#define INS   256
#define HID   512
#define WGS   256
#define GBLK  16   // blocks per group
#define NGRP  16   // groups; group g handles batches g and g+16

__global__ void __launch_bounds__(WGS, 1)
lstm_ebm_fp32(const float* __restrict__ x,
              const float* __restrict__ Wih,
              const float* __restrict__ Whh,
              const float* __restrict__ bias,
              const float* __restrict__ Wout,
              const float* __restrict__ bout,
              float* __restrict__ out,
              float* __restrict__ hglob,   // [2][BATCH][HID] f32
              int* __restrict__ cnt)       // per group: 2 counters, 128B apart
{
#pragma clang fp contract(fast)
  const int wg  = blockIdx.x;
  const int grp = wg & (NGRP - 1);  // blocks of a group ≡ same mod 16 → same mod 8 (XCD heuristic)
  const int j   = wg >> 4;          // block-in-group 0..15
  const int tid = threadIdx.x;
  const int m    = tid >> 3;        // 0..31 : h-index within block's 32-slice
  const int q    = (tid >> 1) & 3;  // gate 0=i 1=f 2=g 3=o
  const int half = tid & 1;         // K-half
  const int row  = q * HID + j * 32 + m;
  const int bA = grp, bB = grp + NGRP;

  __shared__ alignas(16) f32x2 hshA[HID / 2], hshB[HID / 2];
  __shared__ alignas(16) float xshA[2][INS], xshB[2][INS];
  __shared__ float gatA[4][32], gatB[4][32];
  __shared__ float cstA[32], cstB[32];
  __shared__ float red[2][64];

  // ---- persistent fp32 weights in VGPRs: half a row each ----
  f32x2 whh[128];  // 256 f32 of W_hh[row]
  {
    const f32x4* p = reinterpret_cast<const f32x4*>(Whh + (size_t)row * HID + half * 256);
#pragma unroll
    for (int c = 0; c < 64; ++c) { f32x4 v = p[c]; whh[2 * c] = v.xy; whh[2 * c + 1] = v.zw; }
  }
  f32x2 wih[64];   // 128 f32 of W_ih[row]
  {
    const f32x4* p = reinterpret_cast<const f32x4*>(Wih + (size_t)row * INS + half * 128);
#pragma unroll
    for (int c = 0; c < 32; ++c) { f32x4 v = p[c]; wih[2 * c] = v.xy; wih[2 * c + 1] = v.zw; }
  }
  const float bs = half ? 0.0f : bias[row];

  const float* xA = x + (size_t)bA * SEQT * INS;
  const float* xB = x + (size_t)bB * SEQT * INS;

  // ---- init state ----
  hshA[tid] = f32x2{0.f, 0.f};
  hshB[tid] = f32x2{0.f, 0.f};
  xshA[0][tid] = xA[tid];
  xshB[0][tid] = xB[tid];
  if (tid < 32) { cstA[tid] = 0.f; cstB[tid] = 0.f; }
  __syncthreads();

  int* cA = cnt + grp * 64;
  int* cB = cnt + grp * 64 + 32;

#define DOTS(HS, XS, P, OUTV)                                            \
  {                                                                      \
    f32x2 a0{bs, 0.f}, a1{0.f, 0.f}, a2{0.f, 0.f}, a3{0.f, 0.f};         \
    const f32x4* hp = reinterpret_cast<const f32x4*>(HS);                \
    _Pragma("unroll")                                                    \
    for (int c = 0; c < 64; ++c) {                                       \
      f32x4 hv = hp[half * 64 + c];                                      \
      a0 += whh[2 * c] * hv.xy;                                          \
      a1 += whh[2 * c + 1] * hv.zw;                                      \
    }                                                                    \
    const f32x4* xp = reinterpret_cast<const f32x4*>(XS[P]);             \
    _Pragma("unroll")                                                    \
    for (int c = 0; c < 32; ++c) {                                       \
      f32x4 xv = xp[half * 32 + c];                                      \
      a2 += wih[2 * c] * xv.xy;                                          \
      a3 += wih[2 * c + 1] * xv.zw;                                      \
    }                                                                    \
    f32x2 aa = (a0 + a1) + (a2 + a3);                                    \
    OUTV = aa.x + aa.y;                                                  \
  }

#define UPDATE(GAT, CST, BIDX)                                           \
  if (tid < 32) {                                                        \
    float gi = GAT[0][tid], gf = GAT[1][tid], gg = GAT[2][tid], go = GAT[3][tid]; \
    gi = 1.f / (1.f + expf(-gi));                                        \
    gf = 1.f / (1.f + expf(-gf));                                        \
    gg = tanhf(gg);                                                      \
    go = 1.f / (1.f + expf(-go));                                        \
    float cv = gf * CST[tid] + gi * gg;                                  \
    CST[tid] = cv;                                                       \
    hglob[(size_t)pn * BATCH * HID + (size_t)(BIDX) * HID + j * 32 + tid] = go * tanhf(cv); \
  }

  for (int t = 0; t < SEQT; ++t) {
    const int p = t & 1, pn = p ^ 1;
    const int tnext = (t + 1 < SEQT) ? t + 1 : t;
    // x(t+1) prefetch into registers — latency hidden under dots
    float xnA = xA[(size_t)tnext * INS + tid];
    float xnB = xB[(size_t)tnext * INS + tid];

    // ---- batch A: gates, update, arrive ----
    float gA; DOTS(hshA, xshA, p, gA);
    float oA = __shfl_xor(gA, 1);
    if (!half) gatA[q][m] = gA + oA;
    __syncthreads();
    UPDATE(gatA, cstA, bA);
    __syncthreads();  // drains h stores (vmcnt0 before barrier)
    if (tid == 0)
      __hip_atomic_fetch_add(cA, 1, __ATOMIC_RELEASE, __HIP_MEMORY_SCOPE_AGENT);

    // ---- batch B: gates, update, arrive (hides A's barrier propagation) ----
    float gB; DOTS(hshB, xshB, p, gB);
    float oB = __shfl_xor(gB, 1);
    if (!half) gatB[q][m] = gB + oB;
    __syncthreads();
    UPDATE(gatB, cstB, bB);
    __syncthreads();
    if (tid == 0)
      __hip_atomic_fetch_add(cB, 1, __ATOMIC_RELEASE, __HIP_MEMORY_SCOPE_AGENT);

    // ---- wait + stage A ----
    const int tgt = GBLK * (t + 1);
    if (tid == 0) {
      while (__hip_atomic_load(cA, __ATOMIC_RELAXED, __HIP_MEMORY_SCOPE_AGENT) < tgt)
        __builtin_amdgcn_s_sleep(1);
      (void)__hip_atomic_load(cA, __ATOMIC_ACQUIRE, __HIP_MEMORY_SCOPE_AGENT);
    }
    __syncthreads();
    hshA[tid] = reinterpret_cast<const f32x2*>(hglob + (size_t)pn * BATCH * HID + (size_t)bA * HID)[tid];
    xshA[pn][tid] = xnA;

    // ---- wait + stage B ----
    if (tid == 0) {
      while (__hip_atomic_load(cB, __ATOMIC_RELAXED, __HIP_MEMORY_SCOPE_AGENT) < tgt)
        __builtin_amdgcn_s_sleep(1);
      (void)__hip_atomic_load(cB, __ATOMIC_ACQUIRE, __HIP_MEMORY_SCOPE_AGENT);
    }
    __syncthreads();
    hshB[tid] = reinterpret_cast<const f32x2*>(hglob + (size_t)pn * BATCH * HID + (size_t)bB * HID)[tid];
    xshB[pn][tid] = xnB;
    __syncthreads();
  }

  // ---- energy readout (block 0 of each group; hshA/hshB hold h_final) ----
  if (j == 0) {
    if (tid < 64) {
      const float* hA = reinterpret_cast<const float*>(hshA);
      const float* hB = reinterpret_cast<const float*>(hshB);
      float sA = 0.f, sB = 0.f;
#pragma unroll
      for (int e = 0; e < 8; ++e) {
        float w = Wout[tid * 8 + e];
        sA += hA[tid * 8 + e] * w;
        sB += hB[tid * 8 + e] * w;
      }
      red[0][tid] = sA; red[1][tid] = sB;
    }
    __syncthreads();
    if (tid == 0) {
      float sA = bout[0], sB = bout[0];
      for (int e = 0; e < 64; ++e) { sA += red[0][e]; sB += red[1][e]; }
      out[bA] = sA;
      out[bB] = sB;
    }
  }
}

extern "C" void kernel_launch(void* const* d_in, const int* in_sizes, int n_in,
                              void* d_out, int out_size, void* d_ws, size_t ws_size,
                              hipStream_t stream) {
  const float* x    = (const float*)d_in[0];
  const float* Wih  = (const float*)d_in[1];
  const float* Whh  = (const float*)d_in[2];
  const float* bias = (const float*)d_in[3];
  const float* Wout = (const float*)d_in[4];
  const float* bout = (const float*)d_in[5];
  float* out = (float*)d_out;

  float* hglob = (float*)d_ws;                   // 2*32*512*4 = 131072 B
  int* cnt = (int*)((char*)d_ws + 131072);       // 16 groups * 256 B = 4096 B

  hipMemsetAsync(d_ws, 0, 131072 + 4096, stream);

  // Plain launch: grid == 256 CUs, ~430 VGPR/thread -> exactly 1 block/CU, so
  // all 256 blocks are co-resident (persistent-kernel pattern). Cooperative
  // launch was failing silently (round 5/6 bit-identical zero-output absmax)
  // and is not graph-capturable anyway.
  lstm_ebm_fp32<<<dim3(NGRP * GBLK), dim3(WGS), 0, stream>>>(
      x, Wih, Whh, bias, Wout, bout, out, hglob, cnt);
}

// Round 12
// 25107.573 us; speedup vs baseline: 2.2479x; 2.2479x over previous
//
#include <hip/hip_runtime.h>

typedef float f32x2 __attribute__((ext_vector_type(2)));
typedef float f32x4 __attribute__((ext_vector_type(4)));

#define BATCH 32
#define SEQT  4096
#define INS   256
#define HID   512
#define WGS   512
#define GBLK  16   // blocks per group
#define NGRP  16   // groups; group g owns batches g and g+16

__global__ void __launch_bounds__(WGS, 2)
lstm_ebm_fp32(const float* __restrict__ x,
              const float* __restrict__ Wih,
              const float* __restrict__ Whh,
              const float* __restrict__ bias,
              const float* __restrict__ Wout,
              const float* __restrict__ bout,
              float* __restrict__ out,
              float* __restrict__ hglob,   // [2][BATCH][HID] f32
              int* __restrict__ cnt)       // one counter per group, 256B stride
{
#pragma clang fp contract(fast)
  const int wg  = blockIdx.x;
  const int grp = wg & (NGRP - 1);   // bid ≡ grp (mod 16) → same XCD class (heuristic only)
  const int j   = wg >> 4;           // block-in-group 0..15
  const int tid = threadIdx.x;
  const int qtr = tid >> 7;          // K-quarter 0..3 — WAVE-UNIFORM → LDS broadcast reads
  const int r   = tid & 127;         // row-local 0..127
  const int q   = r >> 5;            // gate 0=i 1=f 2=g 3=o
  const int m   = r & 31;            // h index within block's 32-slice
  const int row = q * HID + j * 32 + m;
  const int bA = grp, bB = grp + NGRP;

  __shared__ alignas(16) float hshA[HID], hshB[HID];
  __shared__ alignas(16) float xshA[2][INS], xshB[2][INS];
  __shared__ float gatA[4][128], gatB[4][128];  // [quarter][row-local] partials
  __shared__ float cstA[32], cstB[32];
  __shared__ float red[2][64];

  // ---- persistent fp32 weights: quarter of a row per thread (192 f32 -> fits 256 VGPR) ----
  f32x2 whh[64];   // 128 f32 of W_hh[row]
  {
    const f32x4* pw = reinterpret_cast<const f32x4*>(Whh + (size_t)row * HID + qtr * 128);
#pragma unroll
    for (int c = 0; c < 32; ++c) { f32x4 v = pw[c]; whh[2 * c] = v.xy; whh[2 * c + 1] = v.zw; }
  }
  f32x2 wih[32];   // 64 f32 of W_ih[row]
  {
    const f32x4* pw = reinterpret_cast<const f32x4*>(Wih + (size_t)row * INS + qtr * 64);
#pragma unroll
    for (int c = 0; c < 16; ++c) { f32x4 v = pw[c]; wih[2 * c] = v.xy; wih[2 * c + 1] = v.zw; }
  }
  const float bs = (qtr == 0) ? bias[row] : 0.0f;

  const float* xA = x + (size_t)bA * SEQT * INS;
  const float* xB = x + (size_t)bB * SEQT * INS;

  // ---- init state ----
  hshA[tid] = 0.f;           // WGS == HID == 512
  hshB[tid] = 0.f;
  if (tid < INS) xshA[0][tid] = xA[tid];
  else if (tid < 2 * INS) xshB[0][tid - INS] = xB[tid - INS];
  if (tid < 32) { cstA[tid] = 0.f; cstB[tid] = 0.f; }
  __syncthreads();

  int* mycnt = cnt + grp * 64;   // 256B-padded counter

  for (int t = 0; t < SEQT; ++t) {
    const int p = t & 1, pn = p ^ 1;
    const int tnext = (t + 1 < SEQT) ? t + 1 : t;
    // x(t+1) prefetch into registers; latency hidden under dots
    float xn;
    if (tid < INS) xn = xA[(size_t)tnext * INS + tid];
    else           xn = xB[(size_t)tnext * INS + (tid - INS)];

    // ---- batch A dots (wave-uniform LDS addresses -> broadcast, no conflicts) ----
    {
      f32x2 a0{bs, 0.f}, a1{0.f, 0.f};
      const f32x4* hp = reinterpret_cast<const f32x4*>(hshA) + qtr * 32;
#pragma unroll
      for (int c = 0; c < 32; ++c) { f32x4 hv = hp[c]; a0 += whh[2 * c] * hv.xy; a1 += whh[2 * c + 1] * hv.zw; }
      const f32x4* xp = reinterpret_cast<const f32x4*>(xshA[p]) + qtr * 16;
#pragma unroll
      for (int c = 0; c < 16; ++c) { f32x4 xv = xp[c]; a0 += wih[2 * c] * xv.xy; a1 += wih[2 * c + 1] * xv.zw; }
      f32x2 aa = a0 + a1;
      gatA[qtr][r] = aa.x + aa.y;
    }
    // ---- batch B dots ----
    {
      f32x2 a0{bs, 0.f}, a1{0.f, 0.f};
      const f32x4* hp = reinterpret_cast<const f32x4*>(hshB) + qtr * 32;
#pragma unroll
      for (int c = 0; c < 32; ++c) { f32x4 hv = hp[c]; a0 += whh[2 * c] * hv.xy; a1 += whh[2 * c + 1] * hv.zw; }
      const f32x4* xp = reinterpret_cast<const f32x4*>(xshB[p]) + qtr * 16;
#pragma unroll
      for (int c = 0; c < 16; ++c) { f32x4 xv = xp[c]; a0 += wih[2 * c] * xv.xy; a1 += wih[2 * c + 1] * xv.zw; }
      f32x2 aa = a0 + a1;
      gatB[qtr][r] = aa.x + aa.y;
    }

    if (tid < INS) xshA[pn][tid] = xn; else xshB[pn][tid - INS] = xn;
    __syncthreads();

    // ---- gate nonlinearities + state update: A on wave 0, B on wave 1 (parallel) ----
    if (tid < 32) {
      const int h = tid;
      float gi = 0.f, gf = 0.f, gg = 0.f, go = 0.f;
#pragma unroll
      for (int qt = 0; qt < 4; ++qt) {
        gi += gatA[qt][h]; gf += gatA[qt][32 + h]; gg += gatA[qt][64 + h]; go += gatA[qt][96 + h];
      }
      gi = 1.f / (1.f + expf(-gi));
      gf = 1.f / (1.f + expf(-gf));
      gg = tanhf(gg);
      go = 1.f / (1.f + expf(-go));
      float cv = gf * cstA[h] + gi * gg;
      cstA[h] = cv;
      hglob[(size_t)pn * BATCH * HID + (size_t)bA * HID + j * 32 + h] = go * tanhf(cv);
    } else if (tid >= 64 && tid < 96) {
      const int h = tid - 64;
      float gi = 0.f, gf = 0.f, gg = 0.f, go = 0.f;
#pragma unroll
      for (int qt = 0; qt < 4; ++qt) {
        gi += gatB[qt][h]; gf += gatB[qt][32 + h]; gg += gatB[qt][64 + h]; go += gatB[qt][96 + h];
      }
      gi = 1.f / (1.f + expf(-gi));
      gf = 1.f / (1.f + expf(-gf));
      gg = tanhf(gg);
      go = 1.f / (1.f + expf(-go));
      float cv = gf * cstB[h] + gi * gg;
      cstB[h] = cv;
      hglob[(size_t)pn * BATCH * HID + (size_t)bB * HID + j * 32 + h] = go * tanhf(cv);
    }
    __syncthreads();  // h stores drained (vmcnt 0) before the release below

    // ---- merged group barrier: ONE release-add + ONE spin per step ----
    if (tid == 0) {
      __hip_atomic_fetch_add(mycnt, 1, __ATOMIC_RELEASE, __HIP_MEMORY_SCOPE_AGENT);
      const int tgt = GBLK * (t + 1);
      while (__hip_atomic_load(mycnt, __ATOMIC_RELAXED, __HIP_MEMORY_SCOPE_AGENT) < tgt)
        __builtin_amdgcn_s_sleep(1);
      (void)__hip_atomic_load(mycnt, __ATOMIC_ACQUIRE, __HIP_MEMORY_SCOPE_AGENT);
    }
    __syncthreads();

    // ---- stage h(t+1): A by threads 0..255, B by 256..511 (parallel) ----
    {
      const f32x2* srcA = reinterpret_cast<const f32x2*>(hglob + (size_t)pn * BATCH * HID + (size_t)bA * HID);
      const f32x2* srcB = reinterpret_cast<const f32x2*>(hglob + (size_t)pn * BATCH * HID + (size_t)bB * HID);
      if (tid < 256) reinterpret_cast<f32x2*>(hshA)[tid] = srcA[tid];
      else           reinterpret_cast<f32x2*>(hshB)[tid - 256] = srcB[tid - 256];
    }
    __syncthreads();
  }

  // ---- energy readout (block 0 of each group; hshA/hshB hold h_final) ----
  if (j == 0) {
    if (tid < 64) {
      float sA = 0.f, sB = 0.f;
#pragma unroll
      for (int e = 0; e < 8; ++e) {
        float w = Wout[tid * 8 + e];
        sA += hshA[tid * 8 + e] * w;
        sB += hshB[tid * 8 + e] * w;
      }
      red[0][tid] = sA; red[1][tid] = sB;
    }
    __syncthreads();
    if (tid == 0) {
      float sA = bout[0], sB = bout[0];
      for (int e = 0; e < 64; ++e) { sA += red[0][e]; sB += red[1][e]; }
      out[bA] = sA;
      out[bB] = sB;
    }
  }
}

extern "C" void kernel_launch(void* const* d_in, const int* in_sizes, int n_in,
                              void* d_out, int out_size, void* d_ws, size_t ws_size,
                              hipStream_t stream) {
  const float* x    = (const float*)d_in[0];
  const float* Wih  = (const float*)d_in[1];
  const float* Whh  = (const float*)d_in[2];
  const float* bias = (const float*)d_in[3];
  const float* Wout = (const float*)d_in[4];
  const float* bout = (const float*)d_in[5];
  float* out = (float*)d_out;

  float* hglob = (float*)d_ws;                   // 2*32*512*4 = 131072 B
  int* cnt = (int*)((char*)d_ws + 131072);       // 16 counters, 256 B stride

  hipMemsetAsync(d_ws, 0, 131072 + 4096, stream);

  // grid == 256 == CU count, 512 thr/block @ <=256 VGPR -> exactly 1 block/CU,
  // all blocks co-resident (proven by round-9 pass); spin barrier is safe.
  lstm_ebm_fp32<<<dim3(NGRP * GBLK), dim3(WGS), 0, stream>>>(
      x, Wih, Whh, bias, Wout, bout, out, hglob, cnt);
}